// Round 1
// baseline (696.544 us; speedup 1.0000x reference)
//
#include <hip/hip_runtime.h>
#include <math.h>

#define BATCH 2048
#define DIN   512
#define NS    256
#define NF    64
#define KG    768    // DIN+NS
#define NG    832    // 256+64+256+256
#define KO    1024   // DIN+NS+NS

__device__ __forceinline__ float sigmoidf_(float x) { return 1.0f / (1.0f + expf(-x)); }

// ---------------- Kernel 1: gate GEMM  C[2048,832] = x_h @ [Wf|Wq|Wi|Wc] + act ----
__global__ __launch_bounds__(256) void gates_gemm(
    const float* __restrict__ x, const float* __restrict__ h,
    const float* __restrict__ Wf, const float* __restrict__ bf,
    const float* __restrict__ Wq, const float* __restrict__ bq,
    const float* __restrict__ Wi, const float* __restrict__ bi,
    const float* __restrict__ Wc, const float* __restrict__ bc,
    float* __restrict__ gates)
{
    __shared__ float As[64][33];
    __shared__ float Bs[32][65];

    const int nt = blockIdx.x;   // 0..12
    const int mt = blockIdx.y;   // 0..31
    const int t  = threadIdx.x;

    const int n0 = nt * 64;
    const float* Wp; const float* bp; int ld, noff, act;
    if (n0 < 256)      { Wp = Wf; bp = bf; ld = 256; noff = 0;   act = 0; }
    else if (n0 < 320) { Wp = Wq; bp = bq; ld = 64;  noff = 256; act = 0; }
    else if (n0 < 576) { Wp = Wi; bp = bi; ld = 256; noff = 320; act = 0; }
    else               { Wp = Wc; bp = bc; ld = 256; noff = 576; act = 1; }
    const int nloc0 = n0 - noff;

    const int tx = t & 15, ty = t >> 4;
    const int m0 = mt * 64;
    float acc[4][4] = {};

    for (int kt = 0; kt < KG; kt += 32) {
        #pragma unroll
        for (int it = 0; it < 8; ++it) {
            int lin = t + 256 * it;
            int row = lin >> 5, kk = lin & 31;
            int m = m0 + row, k = kt + kk;
            As[row][kk] = (k < DIN) ? x[m * DIN + k] : h[m * NS + (k - DIN)];
        }
        #pragma unroll
        for (int it = 0; it < 8; ++it) {
            int lin = t + 256 * it;
            int kk = lin >> 6, ni = lin & 63;
            Bs[kk][ni] = Wp[(kt + kk) * ld + nloc0 + ni];
        }
        __syncthreads();
        #pragma unroll
        for (int kk = 0; kk < 32; ++kk) {
            float a[4], bv[4];
            #pragma unroll
            for (int r = 0; r < 4; ++r) a[r] = As[ty * 4 + r][kk];
            #pragma unroll
            for (int c = 0; c < 4; ++c) bv[c] = Bs[kk][tx * 4 + c];
            #pragma unroll
            for (int r = 0; r < 4; ++r)
                #pragma unroll
                for (int c = 0; c < 4; ++c)
                    acc[r][c] = fmaf(a[r], bv[c], acc[r][c]);
        }
        __syncthreads();
    }

    #pragma unroll
    for (int r = 0; r < 4; ++r) {
        int m = m0 + ty * 4 + r;
        #pragma unroll
        for (int c = 0; c < 4; ++c) {
            int nl = nloc0 + tx * 4 + c;
            float v = acc[r][c] + bp[nl];
            v = act ? tanhf(v) : sigmoidf_(v);
            gates[m * NG + n0 + tx * 4 + c] = v;
        }
    }
}

// ---------------- Kernel 2: S update + A·u_a reduction -> c_t ---------------------
// one 16-lane group per (b,s); each lane handles 4 freqs via float4
__global__ __launch_bounds__(256) void supdate(
    const float* __restrict__ S, const float* __restrict__ gates,
    const float* __restrict__ ua, const float* __restrict__ ba,
    const int* __restrict__ tptr,
    float* __restrict__ Sout, float* __restrict__ ct)
{
    const int tid = blockIdx.x * 256 + threadIdx.x;
    const int q    = tid & 15;       // lane within group
    const int pair = tid >> 4;       // (b,s) flat index
    const int b = pair >> 8, s = pair & 255;
    const int f0 = q * 4;
    const int tv = *tptr;

    const float* grow = gates + b * NG;
    const float fste = grow[s];
    const float ic   = grow[320 + s] * grow[576 + s];

    const float4 ff  = *(const float4*)(grow + 256 + f0);
    const float4 ua4 = *(const float4*)(ua + f0);

    const size_t base0 = (((size_t)b * 2 + 0) * NS + s) * NF + f0;
    const size_t base1 = (((size_t)b * 2 + 1) * NS + s) * NF + f0;
    const float4 si0 = *(const float4*)(S + base0);
    const float4 si1 = *(const float4*)(S + base1);

    float fv[4] = { ff.x, ff.y, ff.z, ff.w };
    float uv[4] = { ua4.x, ua4.y, ua4.z, ua4.w };
    float a0[4] = { si0.x, si0.y, si0.z, si0.w };
    float a1[4] = { si1.x, si1.y, si1.z, si1.w };

    float part = 0.0f;
    float o0[4], o1[4];
    #pragma unroll
    for (int j = 0; j < 4; ++j) {
        int f = f0 + j;
        float ang = (float)((f * tv) & (NF - 1)) * (float)(M_PI / 32.0);
        float sn, cs;
        sincosf(ang, &sn, &cs);
        float F = fste * fv[j];
        float u = a0[j] * F + ic * sn;
        float v = a1[j] * F + ic * cs;
        o0[j] = u; o1[j] = v;
        part += sqrtf(u * u + v * v) * uv[j];
    }
    *(float4*)(Sout + base0) = make_float4(o0[0], o0[1], o0[2], o0[3]);
    *(float4*)(Sout + base1) = make_float4(o1[0], o1[1], o1[2], o1[3]);

    part += __shfl_xor(part, 1);
    part += __shfl_xor(part, 2);
    part += __shfl_xor(part, 4);
    part += __shfl_xor(part, 8);
    if (q == 0) ct[pair] = sigmoidf_(part + ba[s]);
}

// ---------------- Kernel 3: output GEMM  h = sigmoid([x_h|c_t] @ W_o + b_o) * c_t -
__global__ __launch_bounds__(256) void out_gemm(
    const float* __restrict__ x, const float* __restrict__ h,
    const float* __restrict__ ct,
    const float* __restrict__ Wo, const float* __restrict__ bo,
    float* __restrict__ hout)
{
    __shared__ float As[64][33];
    __shared__ float Bs[32][65];

    const int nt = blockIdx.x;   // 0..3
    const int mt = blockIdx.y;   // 0..31
    const int t  = threadIdx.x;
    const int n0 = nt * 64;
    const int tx = t & 15, ty = t >> 4;
    const int m0 = mt * 64;
    float acc[4][4] = {};

    for (int kt = 0; kt < KO; kt += 32) {
        #pragma unroll
        for (int it = 0; it < 8; ++it) {
            int lin = t + 256 * it;
            int row = lin >> 5, kk = lin & 31;
            int m = m0 + row, k = kt + kk;
            float v;
            if (k < DIN)           v = x[m * DIN + k];
            else if (k < DIN + NS) v = h[m * NS + (k - DIN)];
            else                   v = ct[m * NS + (k - DIN - NS)];
            As[row][kk] = v;
        }
        #pragma unroll
        for (int it = 0; it < 8; ++it) {
            int lin = t + 256 * it;
            int kk = lin >> 6, ni = lin & 63;
            Bs[kk][ni] = Wo[(kt + kk) * NS + n0 + ni];
        }
        __syncthreads();
        #pragma unroll
        for (int kk = 0; kk < 32; ++kk) {
            float a[4], bv[4];
            #pragma unroll
            for (int r = 0; r < 4; ++r) a[r] = As[ty * 4 + r][kk];
            #pragma unroll
            for (int c = 0; c < 4; ++c) bv[c] = Bs[kk][tx * 4 + c];
            #pragma unroll
            for (int r = 0; r < 4; ++r)
                #pragma unroll
                for (int c = 0; c < 4; ++c)
                    acc[r][c] = fmaf(a[r], bv[c], acc[r][c]);
        }
        __syncthreads();
    }

    #pragma unroll
    for (int r = 0; r < 4; ++r) {
        int m = m0 + ty * 4 + r;
        #pragma unroll
        for (int c = 0; c < 4; ++c) {
            int n = n0 + tx * 4 + c;
            float o = sigmoidf_(acc[r][c] + bo[n]);
            hout[m * NS + n] = o * ct[m * NS + n];
        }
    }
}

extern "C" void kernel_launch(void* const* d_in, const int* in_sizes, int n_in,
                              void* d_out, int out_size, void* d_ws, size_t ws_size,
                              hipStream_t stream)
{
    const float* x  = (const float*)d_in[0];
    const float* h  = (const float*)d_in[1];
    const float* S  = (const float*)d_in[2];
    const float* Wf = (const float*)d_in[3];
    const float* bf = (const float*)d_in[4];
    const float* Wq = (const float*)d_in[5];
    const float* bq = (const float*)d_in[6];
    const float* Wi = (const float*)d_in[7];
    const float* bi = (const float*)d_in[8];
    const float* Wc = (const float*)d_in[9];
    const float* bc = (const float*)d_in[10];
    const float* ua = (const float*)d_in[11];
    const float* ba = (const float*)d_in[12];
    const float* Wo = (const float*)d_in[13];
    const float* bo = (const float*)d_in[14];
    const int*   tp = (const int*)d_in[15];

    float* gates = (float*)d_ws;                       // [B, 832]
    float* ct    = gates + (size_t)BATCH * NG;         // [B, 256]
    float* hout  = (float*)d_out;                      // [B, 256]
    float* Sout  = hout + (size_t)BATCH * NS;          // [B, 2, 256, 64]

    gates_gemm<<<dim3(13, 32), 256, 0, stream>>>(x, h, Wf, bf, Wq, bq, Wi, bi, Wc, bc, gates);
    supdate<<<dim3((BATCH * NS * 16) / 256), 256, 0, stream>>>(S, gates, ua, ba, tp, Sout, ct);
    out_gemm<<<dim3(4, 32), 256, 0, stream>>>(x, h, ct, Wo, bo, hout);
}

// Round 3
// 603.106 us; speedup vs baseline: 1.1549x; 1.1549x over previous
//
#include <hip/hip_runtime.h>
#include <math.h>

#define BATCH 2048
#define DIN   512
#define NS    256
#define NF    64
#define KG    768    // DIN+NS
#define NG    832    // 256+64+256+256
#define KO    1024   // DIN+NS+NS

__device__ __forceinline__ float sigmoidf_(float x) { return 1.0f / (1.0f + __expf(-x)); }

// ---------------- Kernel 1: gate GEMM  C[2048,832] = x_h @ [Wf|Wq|Wi|Wc] + act ----
// BM=64 BN=64 BK=16, 256 threads, 4x4 per-thread tile.
// As stored k-major (transposed) so inner loop reads are 2x ds_read_b128.
__global__ __launch_bounds__(256) void gates_gemm(
    const float* __restrict__ x, const float* __restrict__ h,
    const float* __restrict__ Wf, const float* __restrict__ bf,
    const float* __restrict__ Wq, const float* __restrict__ bq,
    const float* __restrict__ Wi, const float* __restrict__ bi,
    const float* __restrict__ Wc, const float* __restrict__ bcg,
    float* __restrict__ gates)
{
    __shared__ float As[16][68];   // [k][m], row = 272 B (16B-aligned)
    __shared__ float Bs[16][68];   // [k][n]

    const int nt = blockIdx.x;   // 0..12
    const int mt = blockIdx.y;   // 0..31
    const int t  = threadIdx.x;

    const int n0 = nt * 64;
    const float* Wp; const float* bp; int ld, noff, act;
    if (n0 < 256)      { Wp = Wf; bp = bf;  ld = 256; noff = 0;   act = 0; }
    else if (n0 < 320) { Wp = Wq; bp = bq;  ld = 64;  noff = 256; act = 0; }
    else if (n0 < 576) { Wp = Wi; bp = bi;  ld = 256; noff = 320; act = 0; }
    else               { Wp = Wc; bp = bcg; ld = 256; noff = 576; act = 1; }
    const int nloc0 = n0 - noff;

    const int tx = t & 15, ty = t >> 4;
    const int m0 = mt * 64;

    // A-load mapping: one float4 along k per thread
    const int ar = t >> 2;          // 0..63 (row within tile)
    const int ak = (t & 3) * 4;     // 0,4,8,12
    // B-load mapping: one float4 along n per thread
    const int bk   = t >> 4;        // 0..15
    const int bcol = (t & 15) * 4;  // 0..60

    float acc[4][4] = {};

    for (int kt = 0; kt < KG; kt += 16) {
        // stage A (transposed into k-major)
        {
            const int k = kt + ak;
            const int m = m0 + ar;
            float4 a4 = (k < DIN) ? *(const float4*)(x + (size_t)m * DIN + k)
                                  : *(const float4*)(h + (size_t)m * NS + (k - DIN));
            As[ak + 0][ar] = a4.x; As[ak + 1][ar] = a4.y;
            As[ak + 2][ar] = a4.z; As[ak + 3][ar] = a4.w;
        }
        // stage B
        *(float4*)&Bs[bk][bcol] = *(const float4*)(Wp + (size_t)(kt + bk) * ld + nloc0 + bcol);
        __syncthreads();

        #pragma unroll
        for (int kk = 0; kk < 16; ++kk) {
            float4 a = *(const float4*)&As[kk][ty * 4];
            float4 b = *(const float4*)&Bs[kk][tx * 4];
            float av[4] = { a.x, a.y, a.z, a.w };
            float bv[4] = { b.x, b.y, b.z, b.w };
            #pragma unroll
            for (int r = 0; r < 4; ++r)
                #pragma unroll
                for (int c = 0; c < 4; ++c)
                    acc[r][c] = fmaf(av[r], bv[c], acc[r][c]);
        }
        __syncthreads();
    }

    const float4 bb = *(const float4*)(bp + nloc0 + tx * 4);
    const float bvv[4] = { bb.x, bb.y, bb.z, bb.w };
    #pragma unroll
    for (int r = 0; r < 4; ++r) {
        const int m = m0 + ty * 4 + r;
        #pragma unroll
        for (int c = 0; c < 4; ++c) {
            float v = acc[r][c] + bvv[c];
            v = act ? tanhf(v) : sigmoidf_(v);
            gates[(size_t)m * NG + n0 + tx * 4 + c] = v;
        }
    }
}

// ---------------- Kernel 2: S update + A·u_a reduction -> c_t ---------------------
// one 16-lane group per (b,s); each lane handles 4 freqs via float4
__global__ __launch_bounds__(256) void supdate(
    const float* __restrict__ S, const float* __restrict__ gates,
    const float* __restrict__ ua, const float* __restrict__ ba,
    const int* __restrict__ tptr,
    float* __restrict__ Sout, float* __restrict__ ct)
{
    const int tid = blockIdx.x * 256 + threadIdx.x;
    const int q    = tid & 15;       // lane within group
    const int pair = tid >> 4;       // (b,s) flat index
    const int b = pair >> 8, s = pair & 255;
    const int f0 = q * 4;
    const int tv = *tptr;

    const float* grow = gates + (size_t)b * NG;
    const float fste = grow[s];
    const float ic   = grow[320 + s] * grow[576 + s];

    const float4 ff  = *(const float4*)(grow + 256 + f0);
    const float4 ua4 = *(const float4*)(ua + f0);

    const size_t base0 = (((size_t)b * 2 + 0) * NS + s) * NF + f0;
    const size_t base1 = (((size_t)b * 2 + 1) * NS + s) * NF + f0;
    const float4 si0 = *(const float4*)(S + base0);
    const float4 si1 = *(const float4*)(S + base1);

    float fv[4] = { ff.x, ff.y, ff.z, ff.w };
    float uv[4] = { ua4.x, ua4.y, ua4.z, ua4.w };
    float a0[4] = { si0.x, si0.y, si0.z, si0.w };
    float a1[4] = { si1.x, si1.y, si1.z, si1.w };

    float part = 0.0f;
    float o0[4], o1[4];
    #pragma unroll
    for (int j = 0; j < 4; ++j) {
        int f = f0 + j;
        float ang = (float)((f * tv) & (NF - 1)) * (float)(M_PI / 32.0);
        float sn = __sinf(ang), cs = __cosf(ang);   // v_sin/v_cos, not libm
        float F = fste * fv[j];
        float u = a0[j] * F + ic * sn;
        float v = a1[j] * F + ic * cs;
        o0[j] = u; o1[j] = v;
        part += sqrtf(u * u + v * v) * uv[j];
    }
    *(float4*)(Sout + base0) = make_float4(o0[0], o0[1], o0[2], o0[3]);
    *(float4*)(Sout + base1) = make_float4(o1[0], o1[1], o1[2], o1[3]);

    part += __shfl_xor(part, 1);
    part += __shfl_xor(part, 2);
    part += __shfl_xor(part, 4);
    part += __shfl_xor(part, 8);
    if (q == 0) ct[pair] = sigmoidf_(part + ba[s]);
}

// ---------------- Kernel 3: output GEMM  h = sigmoid([x_h|c_t] @ W_o + b_o) * c_t -
__global__ __launch_bounds__(256) void out_gemm(
    const float* __restrict__ x, const float* __restrict__ h,
    const float* __restrict__ ct,
    const float* __restrict__ Wo, const float* __restrict__ bo,
    float* __restrict__ hout)
{
    __shared__ float As[16][68];
    __shared__ float Bs[16][68];

    const int nt = blockIdx.x;   // 0..3
    const int mt = blockIdx.y;   // 0..31
    const int t  = threadIdx.x;
    const int n0 = nt * 64;
    const int tx = t & 15, ty = t >> 4;
    const int m0 = mt * 64;

    const int ar = t >> 2;
    const int ak = (t & 3) * 4;
    const int bk   = t >> 4;
    const int bcol = (t & 15) * 4;

    float acc[4][4] = {};

    for (int kt = 0; kt < KO; kt += 16) {
        {
            const int k = kt + ak;
            const int m = m0 + ar;
            float4 a4;
            if (k < DIN)           a4 = *(const float4*)(x  + (size_t)m * DIN + k);
            else if (k < DIN + NS) a4 = *(const float4*)(h  + (size_t)m * NS + (k - DIN));
            else                   a4 = *(const float4*)(ct + (size_t)m * NS + (k - DIN - NS));
            As[ak + 0][ar] = a4.x; As[ak + 1][ar] = a4.y;
            As[ak + 2][ar] = a4.z; As[ak + 3][ar] = a4.w;
        }
        *(float4*)&Bs[bk][bcol] = *(const float4*)(Wo + (size_t)(kt + bk) * NS + n0 + bcol);
        __syncthreads();

        #pragma unroll
        for (int kk = 0; kk < 16; ++kk) {
            float4 a = *(const float4*)&As[kk][ty * 4];
            float4 b = *(const float4*)&Bs[kk][tx * 4];
            float av[4] = { a.x, a.y, a.z, a.w };
            float bv[4] = { b.x, b.y, b.z, b.w };
            #pragma unroll
            for (int r = 0; r < 4; ++r)
                #pragma unroll
                for (int c = 0; c < 4; ++c)
                    acc[r][c] = fmaf(av[r], bv[c], acc[r][c]);
        }
        __syncthreads();
    }

    #pragma unroll
    for (int r = 0; r < 4; ++r) {
        const int m = m0 + ty * 4 + r;
        #pragma unroll
        for (int c = 0; c < 4; ++c) {
            const int n = n0 + tx * 4 + c;
            float o = sigmoidf_(acc[r][c] + bo[n]);
            hout[(size_t)m * NS + n] = o * ct[(size_t)m * NS + n];
        }
    }
}

extern "C" void kernel_launch(void* const* d_in, const int* in_sizes, int n_in,
                              void* d_out, int out_size, void* d_ws, size_t ws_size,
                              hipStream_t stream)
{
    const float* x  = (const float*)d_in[0];
    const float* h  = (const float*)d_in[1];
    const float* S  = (const float*)d_in[2];
    const float* Wf = (const float*)d_in[3];
    const float* bf = (const float*)d_in[4];
    const float* Wq = (const float*)d_in[5];
    const float* bq = (const float*)d_in[6];
    const float* Wi = (const float*)d_in[7];
    const float* bi = (const float*)d_in[8];
    const float* Wc = (const float*)d_in[9];
    const float* bc = (const float*)d_in[10];
    const float* ua = (const float*)d_in[11];
    const float* ba = (const float*)d_in[12];
    const float* Wo = (const float*)d_in[13];
    const float* bo = (const float*)d_in[14];
    const int*   tp = (const int*)d_in[15];

    float* gates = (float*)d_ws;                       // [B, 832]
    float* ct    = gates + (size_t)BATCH * NG;         // [B, 256]
    float* hout  = (float*)d_out;                      // [B, 256]
    float* Sout  = hout + (size_t)BATCH * NS;          // [B, 2, 256, 64]

    gates_gemm<<<dim3(13, 32), 256, 0, stream>>>(x, h, Wf, bf, Wq, bq, Wi, bi, Wc, bc, gates);
    supdate<<<dim3((BATCH * NS * 16) / 256), 256, 0, stream>>>(S, gates, ua, ba, tp, Sout, ct);
    out_gemm<<<dim3(4, 32), 256, 0, stream>>>(x, h, ct, Wo, bo, hout);
}